// Round 2
// baseline (682.927 us; speedup 1.0000x reference)
//
#include <hip/hip_runtime.h>

typedef __attribute__((ext_vector_type(8))) short short8;
typedef __attribute__((ext_vector_type(4))) float f32x4;

#define MFMA(a, b, c) __builtin_amdgcn_mfma_f32_16x16x32_bf16(a, b, c, 0, 0, 0)
// XOR-swizzled [64][256] bf16 LDS index (8-elem granule)
#define XS(t, c) (((t) << 8) + ((c) ^ (((t) & 7) << 3)))

__device__ __forceinline__ unsigned int pk2(float lo, float hi) {
    unsigned int a = __float_as_uint(lo), b = __float_as_uint(hi);
    a += 0x7FFFu + ((a >> 16) & 1u);   // RNE
    b += 0x7FFFu + ((b >> 16) & 1u);
    return (a >> 16) | (b & 0xFFFF0000u);
}

// zero-padded K=16 fragment: values in k-slots g*8+{0..3}, zeros in g*8+{4..7}
__device__ __forceinline__ short8 zfrag(uint2 p) {
    union { unsigned int u[4]; short8 s; } t;
    t.u[0] = p.x; t.u[1] = p.y; t.u[2] = 0u; t.u[3] = 0u;
    return t.s;
}

// d_ws: [0..196608) wqkvT bf16 [768][256] (wqkvT[n][k]=w_qkv[k][n]); then wprojT [256][256]
__global__ void prep_w(const float* __restrict__ wqkv, const float* __restrict__ wproj,
                       unsigned short* __restrict__ wT) {
    int idx = blockIdx.x * 256 + threadIdx.x;
    if (idx < 768 * 256) {
        int n = idx >> 8, k = idx & 255;
        wT[idx] = (unsigned short)pk2(wqkv[k * 768 + n], 0.f);
    } else {
        int r = idx - 768 * 256;
        int n = r >> 8, k = r & 255;
        wT[idx] = (unsigned short)pk2(wproj[(k << 8) + n], 0.f);
    }
}

__global__ __launch_bounds__(512, 4)
void winattn(const float* __restrict__ x,
             const float* __restrict__ bqkv,
             const float* __restrict__ bproj,
             const unsigned short* __restrict__ wqkvT,
             const unsigned short* __restrict__ wprojT,
             float* __restrict__ out)
{
    __shared__ unsigned short x_lds[64 * 256];   // 32 KiB
    __shared__ unsigned short o_lds[64 * 256];   // 32 KiB

    const int tid  = threadIdx.x;
    const int h    = tid >> 6;        // wave == head
    const int lane = tid & 63;
    const int g    = lane >> 4;
    const int q16  = lane & 15;

    const int widx = blockIdx.x;
    const int b  = widx >> 10;
    const int wh = (widx >> 5) & 31;
    const int ww = widx & 31;

    // ---- stage x window -> LDS bf16 (swizzled); 512 threads x 32 elems ----
    {
        const int t  = tid >> 3;              // token 0..63
        const int c0 = (tid & 7) << 5;        // channel base
        const int hr = (wh << 3) + (t >> 3);
        const int wc = (ww << 3) + (t & 7);
        const float* rowp = x + (((size_t)b * 256 + hr) * 256 + wc) * 256;
        #pragma unroll
        for (int u = 0; u < 4; ++u) {
            const int c = c0 + (u << 3);
            const float4 f0 = *reinterpret_cast<const float4*>(rowp + c);
            const float4 f1 = *reinterpret_cast<const float4*>(rowp + c + 4);
            union { unsigned int u4[4]; short8 s; } pv;
            pv.u4[0] = pk2(f0.x, f0.y); pv.u4[1] = pk2(f0.z, f0.w);
            pv.u4[2] = pk2(f1.x, f1.y); pv.u4[3] = pk2(f1.z, f1.w);
            *reinterpret_cast<short8*>(&x_lds[XS(t, c)]) = pv.s;
        }
    }
    __syncthreads();

    const f32x4 fz = {0.f, 0.f, 0.f, 0.f};
    const float scale = 0.17677669529663687f;   // 1/sqrt(32)

    // ===== QKV for this wave's head: q,k transposed-orientation; v normal =====
    // pk[m][dt][tt]: lane holds 4 bf16 (packed in uint2):
    //  m=0/1 (q,k): {q,k}[tok = tt*16+q16][d = dt*16+g*4+{0..3}]  (via D=W·xT)
    //  m=2   (v)  :  v[tok = tt*16+g*4+{0..3}][d = dt*16+q16]     (via D=x·W)
    uint2 pk[3][2][4];
    #pragma unroll
    for (int m = 0; m < 3; ++m) {
        const unsigned short* wb = wqkvT + ((size_t)(m * 256 + h * 32)) * 256;
        f32x4 acc[2][4];
        #pragma unroll
        for (int dt = 0; dt < 2; ++dt)
            #pragma unroll
            for (int tt = 0; tt < 4; ++tt) acc[dt][tt] = fz;

        #pragma unroll
        for (int ks = 0; ks < 8; ++ks) {
            const int kc = ks << 5;
            short8 wf[2], xf[4];
            #pragma unroll
            for (int dt = 0; dt < 2; ++dt)
                wf[dt] = *reinterpret_cast<const short8*>(wb + (size_t)(dt * 16 + q16) * 256 + kc + g * 8);
            #pragma unroll
            for (int tt = 0; tt < 4; ++tt)
                xf[tt] = *reinterpret_cast<const short8*>(&x_lds[XS(tt * 16 + q16, kc + g * 8)]);
            #pragma unroll
            for (int dt = 0; dt < 2; ++dt)
                #pragma unroll
                for (int tt = 0; tt < 4; ++tt)
                    acc[dt][tt] = (m < 2) ? MFMA(wf[dt], xf[tt], acc[dt][tt])
                                          : MFMA(xf[tt], wf[dt], acc[dt][tt]);
        }
        if (m < 2) {
            #pragma unroll
            for (int dt = 0; dt < 2; ++dt) {
                const float4 bb = *reinterpret_cast<const float4*>(bqkv + m * 256 + h * 32 + dt * 16 + g * 4);
                #pragma unroll
                for (int tt = 0; tt < 4; ++tt) {
                    float v0 = acc[dt][tt][0] + bb.x;
                    float v1 = acc[dt][tt][1] + bb.y;
                    float v2 = acc[dt][tt][2] + bb.z;
                    float v3 = acc[dt][tt][3] + bb.w;
                    if (m == 0) { v0 *= scale; v1 *= scale; v2 *= scale; v3 *= scale; }
                    pk[m][dt][tt] = make_uint2(pk2(v0, v1), pk2(v2, v3));
                }
            }
        } else {
            #pragma unroll
            for (int dt = 0; dt < 2; ++dt) {
                const float bv = bqkv[512 + h * 32 + dt * 16 + q16];
                #pragma unroll
                for (int tt = 0; tt < 4; ++tt) {
                    pk[2][dt][tt] = make_uint2(pk2(acc[dt][tt][0] + bv, acc[dt][tt][1] + bv),
                                               pk2(acc[dt][tt][2] + bv, acc[dt][tt][3] + bv));
                }
            }
        }
    }

    // ===== S^T = K · Q^T (K=16 zero-pad trick), softmax over keys, pack P^T =====
    // ST tile(kt,qt): lane holds ST[key=kt*16+g*4+r][qtok=qt*16+q16]
    uint2 ppk[4][4];   // [kt][qt]: P^T[key=kt*16+g*4+{0..3}][qtok=qt*16+q16]
    #pragma unroll
    for (int qt = 0; qt < 4; ++qt) {
        f32x4 st[4];
        #pragma unroll
        for (int kt = 0; kt < 4; ++kt) st[kt] = fz;
        #pragma unroll
        for (int dt = 0; dt < 2; ++dt) {
            const short8 qf = zfrag(pk[0][dt][qt]);
            #pragma unroll
            for (int kt = 0; kt < 4; ++kt)
                st[kt] = MFMA(zfrag(pk[1][dt][kt]), qf, st[kt]);
        }
        float mx = st[0][0];
        #pragma unroll
        for (int kt = 0; kt < 4; ++kt)
            #pragma unroll
            for (int r = 0; r < 4; ++r) mx = fmaxf(mx, st[kt][r]);
        mx = fmaxf(mx, __shfl_xor(mx, 16));
        mx = fmaxf(mx, __shfl_xor(mx, 32));
        float pe[4][4];
        float sum = 0.f;
        #pragma unroll
        for (int kt = 0; kt < 4; ++kt)
            #pragma unroll
            for (int r = 0; r < 4; ++r) { pe[kt][r] = __expf(st[kt][r] - mx); sum += pe[kt][r]; }
        sum += __shfl_xor(sum, 16);
        sum += __shfl_xor(sum, 32);
        const float inv = 1.f / sum;
        #pragma unroll
        for (int kt = 0; kt < 4; ++kt)
            ppk[kt][qt] = make_uint2(pk2(pe[kt][0] * inv, pe[kt][1] * inv),
                                     pk2(pe[kt][2] * inv, pe[kt][3] * inv));
    }

    // ===== O^T = V^T · P^T (K=16 zero-pad): all-register =====
    f32x4 ot[2][4];    // [DT][TT]: lane: O[tok=TT*16+q16][d=h*32+DT*16+g*4+r]
    #pragma unroll
    for (int dt = 0; dt < 2; ++dt)
        #pragma unroll
        for (int tt = 0; tt < 4; ++tt) ot[dt][tt] = fz;
    #pragma unroll
    for (int kt = 0; kt < 4; ++kt) {
        short8 vf[2];
        #pragma unroll
        for (int dt = 0; dt < 2; ++dt) vf[dt] = zfrag(pk[2][dt][kt]);
        #pragma unroll
        for (int tt = 0; tt < 4; ++tt) {
            const short8 pf = zfrag(ppk[kt][tt]);
            #pragma unroll
            for (int dt = 0; dt < 2; ++dt)
                ot[dt][tt] = MFMA(vf[dt], pf, ot[dt][tt]);
        }
    }
    // write O to LDS (swizzled, b64 per tile)
    #pragma unroll
    for (int dt = 0; dt < 2; ++dt)
        #pragma unroll
        for (int tt = 0; tt < 4; ++tt) {
            const int tok = tt * 16 + q16;
            const int d   = h * 32 + dt * 16 + g * 4;
            const uint2 pv = make_uint2(pk2(ot[dt][tt][0], ot[dt][tt][1]),
                                        pk2(ot[dt][tt][2], ot[dt][tt][3]));
            *reinterpret_cast<uint2*>(&o_lds[XS(tok, d)]) = pv;
        }
    __syncthreads();

    // ===== proj: out[:, h*32 .. h*32+32) = O[64][256] @ wproj + bias =====
    f32x4 pacc[4][2];
    #pragma unroll
    for (int mt = 0; mt < 4; ++mt)
        #pragma unroll
        for (int nt = 0; nt < 2; ++nt) pacc[mt][nt] = fz;
    #pragma unroll
    for (int ks = 0; ks < 8; ++ks) {
        const int kc = ks << 5;
        short8 of[4], wf[2];
        #pragma unroll
        for (int mt = 0; mt < 4; ++mt)
            of[mt] = *reinterpret_cast<const short8*>(&o_lds[XS(mt * 16 + q16, kc + g * 8)]);
        #pragma unroll
        for (int nt = 0; nt < 2; ++nt)
            wf[nt] = *reinterpret_cast<const short8*>(wprojT + (size_t)(h * 32 + nt * 16 + q16) * 256 + kc + g * 8);
        #pragma unroll
        for (int mt = 0; mt < 4; ++mt)
            #pragma unroll
            for (int nt = 0; nt < 2; ++nt)
                pacc[mt][nt] = MFMA(of[mt], wf[nt], pacc[mt][nt]);
    }
    // epilogue
    #pragma unroll
    for (int nt = 0; nt < 2; ++nt) {
        const int oc = h * 32 + nt * 16 + q16;
        const float bp = bproj[oc];
        #pragma unroll
        for (int mt = 0; mt < 4; ++mt) {
            #pragma unroll
            for (int r = 0; r < 4; ++r) {
                const int tok = mt * 16 + g * 4 + r;
                const int hr  = (wh << 3) + (tok >> 3);
                const int wc  = (ww << 3) + (tok & 7);
                out[(((size_t)b * 256 + hr) * 256 + wc) * 256 + oc] = pacc[mt][nt][r] + bp;
            }
        }
    }
}

extern "C" void kernel_launch(void* const* d_in, const int* in_sizes, int n_in,
                              void* d_out, int out_size, void* d_ws, size_t ws_size,
                              hipStream_t stream) {
    const float* x     = (const float*)d_in[0];
    const float* wqkv  = (const float*)d_in[1];
    const float* bqkv  = (const float*)d_in[2];
    const float* wproj = (const float*)d_in[3];
    const float* bproj = (const float*)d_in[4];
    float* out = (float*)d_out;
    unsigned short* wT = (unsigned short*)d_ws;   // 524288 bytes used

    prep_w<<<1024, 256, 0, stream>>>(wqkv, wproj, wT);
    winattn<<<4096, 512, 0, stream>>>(x, bqkv, bproj, wT, wT + 768 * 256, out);
}

// Round 3
// 381.618 us; speedup vs baseline: 1.7896x; 1.7896x over previous
//
#include <hip/hip_runtime.h>
#include <hip/hip_bf16.h>

typedef __attribute__((ext_vector_type(8))) short short8;
typedef __attribute__((ext_vector_type(4))) float f32x4;

#define MFMA(a, b, c) __builtin_amdgcn_mfma_f32_16x16x32_bf16(a, b, c, 0, 0, 0)
// XOR-swizzled [64][256] bf16 LDS index (8-elem granule)
#define XS(t, c) (((t) << 8) + ((c) ^ (((t) & 7) << 3)))

__device__ __forceinline__ unsigned int pk2(float lo, float hi) {
    union { __hip_bfloat162 h2; unsigned int u; } cv;
    cv.h2 = __float22bfloat162_rn(make_float2(lo, hi));
    return cv.u;
}

__device__ __forceinline__ unsigned short f2bf1(float f) {
    unsigned int u = __float_as_uint(f);
    u += 0x7FFFu + ((u >> 16) & 1u);
    return (unsigned short)(u >> 16);
}

// zero-padded K=16 fragment: values in k-slots g*8+{0..3}, zeros in g*8+{4..7}
__device__ __forceinline__ short8 zfrag(uint2 p) {
    union { unsigned int u[4]; short8 s; } t;
    t.u[0] = p.x; t.u[1] = p.y; t.u[2] = 0u; t.u[3] = 0u;
    return t.s;
}

// d_ws: [0..196608) wqkvT bf16 [768][256] (wqkvT[n][k]=w_qkv[k][n]); then wprojT [256][256]
__global__ void prep_w(const float* __restrict__ wqkv, const float* __restrict__ wproj,
                       unsigned short* __restrict__ wT) {
    int idx = blockIdx.x * 256 + threadIdx.x;
    if (idx < 768 * 256) {
        int n = idx >> 8, k = idx & 255;
        wT[idx] = f2bf1(wqkv[k * 768 + n]);
    } else {
        int r = idx - 768 * 256;
        int n = r >> 8, k = r & 255;
        wT[idx] = f2bf1(wproj[(k << 8) + n]);
    }
}

__global__ __launch_bounds__(512, 2)
void winattn(const float* __restrict__ x,
             const float* __restrict__ bqkv,
             const float* __restrict__ bproj,
             const unsigned short* __restrict__ wqkvT,
             const unsigned short* __restrict__ wprojT,
             float* __restrict__ out)
{
    __shared__ unsigned short smem[64 * 256];   // 32 KiB: x, then O (after barrier)

    const int tid  = threadIdx.x;
    const int h    = tid >> 6;        // wave == head
    const int lane = tid & 63;
    const int g    = lane >> 4;
    const int q16  = lane & 15;

    const int widx = blockIdx.x;
    const int b  = widx >> 10;
    const int wh = (widx >> 5) & 31;
    const int ww = widx & 31;

    // ---- stage x window -> LDS bf16 (swizzled); 8 lanes read 256B contiguous ----
    {
        const int t  = tid >> 3;              // token 0..63
        const int c0 = (tid & 7) << 3;        // channel base
        const int hr = (wh << 3) + (t >> 3);
        const int wc = (ww << 3) + (t & 7);
        const float* rowp = x + (((size_t)b * 256 + hr) * 256 + wc) * 256;
        #pragma unroll
        for (int u = 0; u < 4; ++u) {
            const int c = c0 + (u << 6);
            const float4 f0 = *reinterpret_cast<const float4*>(rowp + c);
            const float4 f1 = *reinterpret_cast<const float4*>(rowp + c + 4);
            union { unsigned int u4[4]; short8 s; } pv;
            pv.u4[0] = pk2(f0.x, f0.y); pv.u4[1] = pk2(f0.z, f0.w);
            pv.u4[2] = pk2(f1.x, f1.y); pv.u4[3] = pk2(f1.z, f1.w);
            *reinterpret_cast<short8*>(&smem[XS(t, c)]) = pv.s;
        }
    }
    __syncthreads();

    const f32x4 fz = {0.f, 0.f, 0.f, 0.f};
    const float scale = 0.17677669529663687f;   // 1/sqrt(32)

    // ===== fused QKV (single pass over x_lds): =====
    // pk[m][dt][tt]: lane holds 4 bf16 (uint2):
    //  m=0/1 (q,k): {q,k}[tok=tt*16+q16][d=dt*16+g*4+{0..3}]  (D = W·x^T)
    //  m=2   (v)  :  v[tok=tt*16+g*4+{0..3}][d=dt*16+q16]     (D = x·W)
    uint2 pk[3][2][4];
    #pragma unroll
    for (int half = 0; half < 2; ++half) {
        f32x4 acc[3][2][2];
        #pragma unroll
        for (int m = 0; m < 3; ++m)
            #pragma unroll
            for (int dt = 0; dt < 2; ++dt)
                #pragma unroll
                for (int t2 = 0; t2 < 2; ++t2) acc[m][dt][t2] = fz;

        #pragma unroll
        for (int ks = 0; ks < 8; ++ks) {
            const int kc = ks << 5;
            short8 xf[2];
            #pragma unroll
            for (int t2 = 0; t2 < 2; ++t2)
                xf[t2] = *reinterpret_cast<const short8*>(
                    &smem[XS(((half << 1) + t2) * 16 + q16, kc + (g << 3))]);
            #pragma unroll
            for (int m = 0; m < 3; ++m) {
                #pragma unroll
                for (int dt = 0; dt < 2; ++dt) {
                    const short8 wf = *reinterpret_cast<const short8*>(
                        wqkvT + (size_t)(m * 256 + h * 32 + dt * 16 + q16) * 256 + kc + (g << 3));
                    #pragma unroll
                    for (int t2 = 0; t2 < 2; ++t2)
                        acc[m][dt][t2] = (m < 2) ? MFMA(wf, xf[t2], acc[m][dt][t2])
                                                 : MFMA(xf[t2], wf, acc[m][dt][t2]);
                }
            }
        }
        // pack with bias (+scale for q)
        #pragma unroll
        for (int dt = 0; dt < 2; ++dt) {
            #pragma unroll
            for (int m = 0; m < 2; ++m) {
                const float4 bb = *reinterpret_cast<const float4*>(
                    bqkv + m * 256 + h * 32 + dt * 16 + (g << 2));
                const float sc = (m == 0) ? scale : 1.f;
                #pragma unroll
                for (int t2 = 0; t2 < 2; ++t2) {
                    const f32x4 a = acc[m][dt][t2];
                    pk[m][dt][(half << 1) + t2] =
                        make_uint2(pk2((a[0] + bb.x) * sc, (a[1] + bb.y) * sc),
                                   pk2((a[2] + bb.z) * sc, (a[3] + bb.w) * sc));
                }
            }
            const float bv = bqkv[512 + h * 32 + dt * 16 + q16];
            #pragma unroll
            for (int t2 = 0; t2 < 2; ++t2) {
                const f32x4 a = acc[2][dt][t2];
                pk[2][dt][(half << 1) + t2] =
                    make_uint2(pk2(a[0] + bv, a[1] + bv), pk2(a[2] + bv, a[3] + bv));
            }
        }
    }

    // ===== S^T = K·Q^T (K=16 zero-pad), softmax over keys, pack P^T =====
    uint2 ppk[4][4];   // [kt][qt]: P^T[key=kt*16+g*4+{0..3}][qtok=qt*16+q16]
    #pragma unroll
    for (int qt = 0; qt < 4; ++qt) {
        f32x4 st[4];
        #pragma unroll
        for (int kt = 0; kt < 4; ++kt) st[kt] = fz;
        #pragma unroll
        for (int dt = 0; dt < 2; ++dt) {
            const short8 qf = zfrag(pk[0][dt][qt]);
            #pragma unroll
            for (int kt = 0; kt < 4; ++kt)
                st[kt] = MFMA(zfrag(pk[1][dt][kt]), qf, st[kt]);
        }
        float mx = st[0][0];
        #pragma unroll
        for (int kt = 0; kt < 4; ++kt)
            #pragma unroll
            for (int r = 0; r < 4; ++r) mx = fmaxf(mx, st[kt][r]);
        mx = fmaxf(mx, __shfl_xor(mx, 16));
        mx = fmaxf(mx, __shfl_xor(mx, 32));
        float pe[4][4];
        float sum = 0.f;
        #pragma unroll
        for (int kt = 0; kt < 4; ++kt)
            #pragma unroll
            for (int r = 0; r < 4; ++r) { pe[kt][r] = __expf(st[kt][r] - mx); sum += pe[kt][r]; }
        sum += __shfl_xor(sum, 16);
        sum += __shfl_xor(sum, 32);
        const float inv = 1.f / sum;
        #pragma unroll
        for (int kt = 0; kt < 4; ++kt)
            ppk[kt][qt] = make_uint2(pk2(pe[kt][0] * inv, pe[kt][1] * inv),
                                     pk2(pe[kt][2] * inv, pe[kt][3] * inv));
    }

    // ===== O^T = V^T·P^T (K=16 zero-pad): all-register =====
    f32x4 ot[2][4];    // lane: O[tok=tt*16+q16][d=h*32+dt*16+g*4+r]
    #pragma unroll
    for (int dt = 0; dt < 2; ++dt)
        #pragma unroll
        for (int tt = 0; tt < 4; ++tt) ot[dt][tt] = fz;
    #pragma unroll
    for (int kt = 0; kt < 4; ++kt) {
        short8 vf[2];
        #pragma unroll
        for (int dt = 0; dt < 2; ++dt) vf[dt] = zfrag(pk[2][dt][kt]);
        #pragma unroll
        for (int tt = 0; tt < 4; ++tt) {
            const short8 pf = zfrag(ppk[kt][tt]);
            #pragma unroll
            for (int dt = 0; dt < 2; ++dt)
                ot[dt][tt] = MFMA(vf[dt], pf, ot[dt][tt]);
        }
    }

    __syncthreads();   // all waves' x_lds reads complete before O overlay
    #pragma unroll
    for (int dt = 0; dt < 2; ++dt)
        #pragma unroll
        for (int tt = 0; tt < 4; ++tt) {
            const int tok = tt * 16 + q16;
            const int d   = h * 32 + dt * 16 + (g << 2);
            const uint2 pv = make_uint2(pk2(ot[dt][tt][0], ot[dt][tt][1]),
                                        pk2(ot[dt][tt][2], ot[dt][tt][3]));
            *reinterpret_cast<uint2*>(&smem[XS(tok, d)]) = pv;
        }
    __syncthreads();

    // ===== proj: out[:, h*32..h*32+32) = O[64][256] @ wproj + bias =====
    f32x4 pacc[4][2];
    #pragma unroll
    for (int mt = 0; mt < 4; ++mt)
        #pragma unroll
        for (int nt = 0; nt < 2; ++nt) pacc[mt][nt] = fz;
    #pragma unroll
    for (int ks = 0; ks < 8; ++ks) {
        const int kc = ks << 5;
        short8 of[4], wf[2];
        #pragma unroll
        for (int mt = 0; mt < 4; ++mt)
            of[mt] = *reinterpret_cast<const short8*>(&smem[XS(mt * 16 + q16, kc + (g << 3))]);
        #pragma unroll
        for (int nt = 0; nt < 2; ++nt)
            wf[nt] = *reinterpret_cast<const short8*>(
                wprojT + (size_t)(h * 32 + nt * 16 + q16) * 256 + kc + (g << 3));
        #pragma unroll
        for (int mt = 0; mt < 4; ++mt)
            #pragma unroll
            for (int nt = 0; nt < 2; ++nt)
                pacc[mt][nt] = MFMA(of[mt], wf[nt], pacc[mt][nt]);
    }
    // epilogue
    #pragma unroll
    for (int nt = 0; nt < 2; ++nt) {
        const int oc = h * 32 + nt * 16 + q16;
        const float bp = bproj[oc];
        #pragma unroll
        for (int mt = 0; mt < 4; ++mt) {
            #pragma unroll
            for (int r = 0; r < 4; ++r) {
                const int tok = mt * 16 + (g << 2) + r;
                const int hr  = (wh << 3) + (tok >> 3);
                const int wc  = (ww << 3) + (tok & 7);
                out[(((size_t)b * 256 + hr) * 256 + wc) * 256 + oc] = pacc[mt][nt][r] + bp;
            }
        }
    }
}

extern "C" void kernel_launch(void* const* d_in, const int* in_sizes, int n_in,
                              void* d_out, int out_size, void* d_ws, size_t ws_size,
                              hipStream_t stream) {
    const float* x     = (const float*)d_in[0];
    const float* wqkv  = (const float*)d_in[1];
    const float* bqkv  = (const float*)d_in[2];
    const float* wproj = (const float*)d_in[3];
    const float* bproj = (const float*)d_in[4];
    float* out = (float*)d_out;
    unsigned short* wT = (unsigned short*)d_ws;   // 524288 bytes used

    prep_w<<<1024, 256, 0, stream>>>(wqkv, wproj, wT);
    winattn<<<4096, 512, 0, stream>>>(x, bqkv, bproj, wT, wT + 768 * 256, out);
}

// Round 4
// 372.291 us; speedup vs baseline: 1.8344x; 1.0251x over previous
//
#include <hip/hip_runtime.h>
#include <hip/hip_bf16.h>

typedef __attribute__((ext_vector_type(8))) short short8;
typedef __attribute__((ext_vector_type(4))) short short4v;
typedef __attribute__((ext_vector_type(4))) float f32x4;

#define MFMA(a, b, c) __builtin_amdgcn_mfma_f32_16x16x32_bf16(a, b, c, 0, 0, 0)
// XOR-swizzled [64][256] bf16 LDS index (8-elem granule)
#define XS(t, c) (((t) << 8) + ((c) ^ (((t) & 7) << 3)))

__device__ __forceinline__ unsigned int pk2(float lo, float hi) {
    union { __hip_bfloat162 h2; unsigned int u; } cv;
    cv.h2 = __float22bfloat162_rn(make_float2(lo, hi));
    return cv.u;
}

__device__ __forceinline__ unsigned short f2bf1(float f) {
    unsigned int u = __float_as_uint(f);
    u += 0x7FFFu + ((u >> 16) & 1u);
    return (unsigned short)(u >> 16);
}

__device__ __forceinline__ short4v u2s4(uint2 p) {
    union { uint2 u; short4v s; } t; t.u = p; return t.s;
}

#if __has_builtin(__builtin_amdgcn_mfma_f32_16x16x16bf16_1k)
// native K=16 bf16 MFMA: A/B frag = 4 bf16 at k = (lane>>4)*4 + {0..3}, row = lane&15
__device__ __forceinline__ f32x4 mfma16(uint2 a, uint2 b, f32x4 c) {
    return __builtin_amdgcn_mfma_f32_16x16x16bf16_1k(u2s4(a), u2s4(b), c, 0, 0, 0);
}
#else
// fallback: zero-padded K=32 (values at k=g*8+{0..3}, zeros above) — same dot product
__device__ __forceinline__ short8 zfrag(uint2 p) {
    union { unsigned int u[4]; short8 s; } t;
    t.u[0] = p.x; t.u[1] = p.y; t.u[2] = 0u; t.u[3] = 0u;
    return t.s;
}
__device__ __forceinline__ f32x4 mfma16(uint2 a, uint2 b, f32x4 c) {
    return MFMA(zfrag(a), zfrag(b), c);
}
#endif

#if __has_builtin(__builtin_amdgcn_exp2f)
#define EXP2(x) __builtin_amdgcn_exp2f(x)
#else
#define EXP2(x) exp2f(x)
#endif

// d_ws: [0..196608) wqkvT bf16 [768][256] (wqkvT[n][k]=w_qkv[k][n]); then wprojT [256][256]
__global__ void prep_w(const float* __restrict__ wqkv, const float* __restrict__ wproj,
                       unsigned short* __restrict__ wT) {
    int idx = blockIdx.x * 256 + threadIdx.x;
    if (idx < 768 * 256) {
        int n = idx >> 8, k = idx & 255;
        wT[idx] = f2bf1(wqkv[k * 768 + n]);
    } else {
        int r = idx - 768 * 256;
        int n = r >> 8, k = r & 255;
        wT[idx] = f2bf1(wproj[(k << 8) + n]);
    }
}

__global__ __launch_bounds__(512, 2)
void winattn(const float* __restrict__ x,
             const float* __restrict__ bqkv,
             const float* __restrict__ bproj,
             const unsigned short* __restrict__ wqkvT,
             const unsigned short* __restrict__ wprojT,
             float* __restrict__ out)
{
    __shared__ unsigned short smem[64 * 256];   // 32 KiB: x, then O (after barrier)

    const int tid  = threadIdx.x;
    const int h    = tid >> 6;        // wave == head
    const int lane = tid & 63;
    const int g    = lane >> 4;
    const int q16  = lane & 15;

    const int widx = blockIdx.x;
    const int b  = widx >> 10;
    const int wh = (widx >> 5) & 31;
    const int ww = widx & 31;

    // ---- stage x window -> LDS bf16 (swizzled) ----
    {
        const int t  = tid >> 3;              // token 0..63
        const int c0 = (tid & 7) << 3;        // channel base
        const int hr = (wh << 3) + (t >> 3);
        const int wc = (ww << 3) + (t & 7);
        const float* rowp = x + (((size_t)b * 256 + hr) * 256 + wc) * 256;
        #pragma unroll
        for (int u = 0; u < 4; ++u) {
            const int c = c0 + (u << 6);
            const float4 f0 = *reinterpret_cast<const float4*>(rowp + c);
            const float4 f1 = *reinterpret_cast<const float4*>(rowp + c + 4);
            union { unsigned int u4[4]; short8 s; } pv;
            pv.u4[0] = pk2(f0.x, f0.y); pv.u4[1] = pk2(f0.z, f0.w);
            pv.u4[2] = pk2(f1.x, f1.y); pv.u4[3] = pk2(f1.z, f1.w);
            *reinterpret_cast<short8*>(&smem[XS(t, c)]) = pv.s;
        }
    }
    __syncthreads();

    const f32x4 fz = {0.f, 0.f, 0.f, 0.f};
    // scale/sqrt(d) folded with log2(e) into the q-pack -> softmax uses exp2 directly
    const float SCL = 0.17677669529663687f * 1.4426950408889634f;

    // ===== QKV, m-major (weight reuse 4 MFMA per global load) =====
    // pk[m][dt][tt]: lane holds 4 bf16 (uint2):
    //  m=0/1 (q,k): {q,k}[tok=tt*16+q16][d=dt*16+g*4+{0..3}]  (D = W·x^T)  [q pre-scaled]
    //  m=2   (v)  :  v[tok=tt*16+g*4+{0..3}][d=dt*16+q16]     (D = x·W)
    uint2 pk[3][2][4];
    #pragma unroll
    for (int m = 0; m < 3; ++m) {
        f32x4 acc[2][4];
        #pragma unroll
        for (int dt = 0; dt < 2; ++dt)
            #pragma unroll
            for (int tt = 0; tt < 4; ++tt) acc[dt][tt] = fz;

        const unsigned short* wb = wqkvT + (size_t)(m * 256 + h * 32) * 256;
        #pragma unroll
        for (int ks = 0; ks < 8; ++ks) {
            const int kc = ks << 5;
            short8 xf[4];
            #pragma unroll
            for (int tt = 0; tt < 4; ++tt)
                xf[tt] = *reinterpret_cast<const short8*>(&smem[XS(tt * 16 + q16, kc + (g << 3))]);
            #pragma unroll
            for (int dt = 0; dt < 2; ++dt) {
                const short8 wf = *reinterpret_cast<const short8*>(
                    wb + (size_t)(dt * 16 + q16) * 256 + kc + (g << 3));
                #pragma unroll
                for (int tt = 0; tt < 4; ++tt)
                    acc[dt][tt] = (m < 2) ? MFMA(wf, xf[tt], acc[dt][tt])
                                          : MFMA(xf[tt], wf, acc[dt][tt]);
            }
        }
        // pack with bias (+SCL for q)
        if (m < 2) {
            #pragma unroll
            for (int dt = 0; dt < 2; ++dt) {
                const float4 bb = *reinterpret_cast<const float4*>(
                    bqkv + m * 256 + h * 32 + dt * 16 + (g << 2));
                const float sc = (m == 0) ? SCL : 1.f;
                #pragma unroll
                for (int tt = 0; tt < 4; ++tt) {
                    const f32x4 a = acc[dt][tt];
                    pk[m][dt][tt] = make_uint2(pk2((a[0] + bb.x) * sc, (a[1] + bb.y) * sc),
                                               pk2((a[2] + bb.z) * sc, (a[3] + bb.w) * sc));
                }
            }
        } else {
            #pragma unroll
            for (int dt = 0; dt < 2; ++dt) {
                const float bv = bqkv[512 + h * 32 + dt * 16 + q16];
                #pragma unroll
                for (int tt = 0; tt < 4; ++tt) {
                    const f32x4 a = acc[dt][tt];
                    pk[2][dt][tt] = make_uint2(pk2(a[0] + bv, a[1] + bv),
                                               pk2(a[2] + bv, a[3] + bv));
                }
            }
        }
    }

    // ===== S^T = K·Q^T (native K=16), exp2 (no max-sub), unnormalized P^T =====
    uint2 ppk[4][4];   // [kt][qt]: P^T[key=kt*16+g*4+{0..3}][qtok=qt*16+q16]
    float inv4[4];
    #pragma unroll
    for (int qt = 0; qt < 4; ++qt) {
        f32x4 st[4];
        #pragma unroll
        for (int kt = 0; kt < 4; ++kt) st[kt] = fz;
        #pragma unroll
        for (int dt = 0; dt < 2; ++dt)
            #pragma unroll
            for (int kt = 0; kt < 4; ++kt)
                st[kt] = mfma16(pk[1][dt][kt], pk[0][dt][qt], st[kt]);
        float sum = 0.f;
        #pragma unroll
        for (int kt = 0; kt < 4; ++kt) {
            const float e0 = EXP2(st[kt][0]), e1 = EXP2(st[kt][1]);
            const float e2 = EXP2(st[kt][2]), e3 = EXP2(st[kt][3]);
            sum += (e0 + e1) + (e2 + e3);
            ppk[kt][qt] = make_uint2(pk2(e0, e1), pk2(e2, e3));
        }
        sum += __shfl_xor(sum, 16);
        sum += __shfl_xor(sum, 32);
        inv4[qt] = 1.f / sum;
    }

    // ===== O^T = V^T·P^T (native K=16), normalize at the end =====
    f32x4 ot[2][4];    // lane: O[tok=tt*16+q16][d=h*32+dt*16+g*4+r] (pre-normalize)
    #pragma unroll
    for (int dt = 0; dt < 2; ++dt)
        #pragma unroll
        for (int tt = 0; tt < 4; ++tt) ot[dt][tt] = fz;
    #pragma unroll
    for (int kt = 0; kt < 4; ++kt)
        #pragma unroll
        for (int tt = 0; tt < 4; ++tt)
            #pragma unroll
            for (int dt = 0; dt < 2; ++dt)
                ot[dt][tt] = mfma16(pk[2][dt][kt], ppk[kt][tt], ot[dt][tt]);

    __syncthreads();   // all waves' x_lds reads complete before O overlay
    #pragma unroll
    for (int dt = 0; dt < 2; ++dt)
        #pragma unroll
        for (int tt = 0; tt < 4; ++tt) {
            const float iv = inv4[tt];
            const int tok = tt * 16 + q16;
            const int d   = h * 32 + dt * 16 + (g << 2);
            const uint2 pv = make_uint2(pk2(ot[dt][tt][0] * iv, ot[dt][tt][1] * iv),
                                        pk2(ot[dt][tt][2] * iv, ot[dt][tt][3] * iv));
            *reinterpret_cast<uint2*>(&smem[XS(tok, d)]) = pv;
        }
    __syncthreads();

    // ===== proj: out[:, h*32..h*32+32) = O[64][256] @ wproj + bias =====
    f32x4 pacc[4][2];
    #pragma unroll
    for (int mt = 0; mt < 4; ++mt)
        #pragma unroll
        for (int nt = 0; nt < 2; ++nt) pacc[mt][nt] = fz;
    #pragma unroll
    for (int ks = 0; ks < 8; ++ks) {
        const int kc = ks << 5;
        short8 of[4], wf[2];
        #pragma unroll
        for (int mt = 0; mt < 4; ++mt)
            of[mt] = *reinterpret_cast<const short8*>(&smem[XS(mt * 16 + q16, kc + (g << 3))]);
        #pragma unroll
        for (int nt = 0; nt < 2; ++nt)
            wf[nt] = *reinterpret_cast<const short8*>(
                wprojT + (size_t)(h * 32 + nt * 16 + q16) * 256 + kc + (g << 3));
        #pragma unroll
        for (int mt = 0; mt < 4; ++mt)
            #pragma unroll
            for (int nt = 0; nt < 2; ++nt)
                pacc[mt][nt] = MFMA(of[mt], wf[nt], pacc[mt][nt]);
    }
    // epilogue: base + compile-time offsets; tok = mt*16+g*4+r -> hr-part = mt*2+(g>>1),
    // wc-part = (g&1)*4+r; offset(mt,r,nt) = mt*131072 + r*256 + nt*16 elements
    {
        float bp[2];
        #pragma unroll
        for (int nt = 0; nt < 2; ++nt) bp[nt] = bproj[h * 32 + nt * 16 + q16];
        float* obase = out + (((size_t)b * 256 + (wh << 3) + (g >> 1)) * 256
                              + (ww << 3) + ((g & 1) << 2)) * 256 + h * 32 + q16;
        #pragma unroll
        for (int mt = 0; mt < 4; ++mt)
            #pragma unroll
            for (int r = 0; r < 4; ++r)
                #pragma unroll
                for (int nt = 0; nt < 2; ++nt)
                    obase[mt * 131072 + r * 256 + nt * 16] = pacc[mt][nt][r] + bp[nt];
    }
}

extern "C" void kernel_launch(void* const* d_in, const int* in_sizes, int n_in,
                              void* d_out, int out_size, void* d_ws, size_t ws_size,
                              hipStream_t stream) {
    const float* x     = (const float*)d_in[0];
    const float* wqkv  = (const float*)d_in[1];
    const float* bqkv  = (const float*)d_in[2];
    const float* wproj = (const float*)d_in[3];
    const float* bproj = (const float*)d_in[4];
    float* out = (float*)d_out;
    unsigned short* wT = (unsigned short*)d_ws;   // 524288 bytes used

    prep_w<<<1024, 256, 0, stream>>>(wqkv, wproj, wT);
    winattn<<<4096, 512, 0, stream>>>(x, bqkv, bproj, wT, wT + 768 * 256, out);
}